// Round 2
// baseline (902.939 us; speedup 1.0000x reference)
//
#include <hip/hip_runtime.h>
#include <math.h>

#define N_CLS 16384
#define DDIM  128
#define BM 128
#define BN 128
#define BK 16
#define TM 8
#define TN 8
#define SHIFT_C 50.0f   // fixed log-sum-exp shift: exp(logit - C) never overflows
                        // (max logit ~ +100 << C + 88.7) and underflow is negligible

// ---------------------------------------------------------------------------
// prep: ap[i] = dot(x[2i], x[2i+1])  (== dot(anchor_i, positive_i) since the
// pair {anchor,pos} is always {x[2i], x[2i+1]} and dot is symmetric).
// Also zero the row-sum accumulator (ws is poisoned 0xAA before each launch).
// ---------------------------------------------------------------------------
__global__ __launch_bounds__(128)
void prep_kernel(const float* __restrict__ x,
                 float* __restrict__ ap,
                 float* __restrict__ sums) {
    int i = blockIdx.x;
    int t = threadIdx.x;  // 0..127
    float xa = x[(2 * i) * DDIM + t];
    float xb = x[(2 * i + 1) * DDIM + t];
    float prod = xa * xb;
    #pragma unroll
    for (int off = 32; off > 0; off >>= 1)
        prod += __shfl_down(prod, off, 64);
    __shared__ float w[2];
    if ((t & 63) == 0) w[t >> 6] = prod;
    __syncthreads();
    if (t == 0) {
        ap[i] = w[0] + w[1];
        sums[i] = 0.0f;
    }
}

// ---------------------------------------------------------------------------
// fused: S-tile = A-tile @ N-tile^T ; e = exp(S - ap[row] - C) (diag masked);
// row-sums reduced across the tile and atomically added into sums[row].
// A row r = x[2r + anchor_idx[r]], N col c = x[2c + 1]. No S materialization.
// ---------------------------------------------------------------------------
__global__ __launch_bounds__(256)
void fused_kernel(const float* __restrict__ x,
                  const int* __restrict__ aidx,
                  const float* __restrict__ ap,
                  float* __restrict__ sums) {
    __shared__ float As[BK][BM];
    __shared__ float Bs[BK][BN];

    const int tid = threadIdx.x;
    const int tx = tid & 15;
    const int ty = tid >> 4;
    const int rowBase = blockIdx.y * BM;
    const int colBase = blockIdx.x * BN;

    // Staging assignment: thread -> (row m = tid>>1, 8-float chunk kb)
    const int m  = tid >> 1;
    const int kb = (tid & 1) * 8;
    const long arow = 2L * (rowBase + m) + aidx[rowBase + m];
    const long brow = 2L * (colBase + m) + 1;
    const float* aptr = x + arow * DDIM + kb;
    const float* bptr = x + brow * DDIM + kb;

    float acc[TM][TN];
    #pragma unroll
    for (int ii = 0; ii < TM; ++ii)
        #pragma unroll
        for (int jj = 0; jj < TN; ++jj)
            acc[ii][jj] = 0.0f;

    for (int k0 = 0; k0 < DDIM; k0 += BK) {
        float4 va0 = *(const float4*)(aptr + k0);
        float4 va1 = *(const float4*)(aptr + k0 + 4);
        float4 vb0 = *(const float4*)(bptr + k0);
        float4 vb1 = *(const float4*)(bptr + k0 + 4);
        As[kb + 0][m] = va0.x; As[kb + 1][m] = va0.y;
        As[kb + 2][m] = va0.z; As[kb + 3][m] = va0.w;
        As[kb + 4][m] = va1.x; As[kb + 5][m] = va1.y;
        As[kb + 6][m] = va1.z; As[kb + 7][m] = va1.w;
        Bs[kb + 0][m] = vb0.x; Bs[kb + 1][m] = vb0.y;
        Bs[kb + 2][m] = vb0.z; Bs[kb + 3][m] = vb0.w;
        Bs[kb + 4][m] = vb1.x; Bs[kb + 5][m] = vb1.y;
        Bs[kb + 6][m] = vb1.z; Bs[kb + 7][m] = vb1.w;
        __syncthreads();

        #pragma unroll
        for (int k = 0; k < BK; ++k) {
            float af[TM], bf[TN];
            *(float4*)&af[0] = *(const float4*)&As[k][ty * TM];
            *(float4*)&af[4] = *(const float4*)&As[k][ty * TM + 4];
            *(float4*)&bf[0] = *(const float4*)&Bs[k][tx * TN];
            *(float4*)&bf[4] = *(const float4*)&Bs[k][tx * TN + 4];
            #pragma unroll
            for (int ii = 0; ii < TM; ++ii)
                #pragma unroll
                for (int jj = 0; jj < TN; ++jj)
                    acc[ii][jj] = fmaf(af[ii], bf[jj], acc[ii][jj]);
        }
        __syncthreads();
    }

    // Epilogue: exp(logit - C), diagonal mask, per-row reduce across 16 tx lanes.
    #pragma unroll
    for (int ii = 0; ii < TM; ++ii) {
        const int r = rowBase + ty * TM + ii;
        const float apr = ap[r] + SHIFT_C;
        float rs = 0.0f;
        #pragma unroll
        for (int jj = 0; jj < TN; ++jj) {
            const int c = colBase + tx * TN + jj;
            const float e = __expf(acc[ii][jj] - apr);
            rs += (r != c) ? e : 0.0f;
        }
        #pragma unroll
        for (int off = 1; off < 16; off <<= 1)
            rs += __shfl_xor(rs, off, 64);
        if (tx == 0) atomicAdd(&sums[r], rs);
    }
}

// ---------------------------------------------------------------------------
// finalize: out = sum_i [ C + log(exp(-C) + sums[i]) ]   ( == sum_i log1p(S_i) )
// ---------------------------------------------------------------------------
__global__ __launch_bounds__(256)
void finalize_kernel(const float* __restrict__ sums, float* __restrict__ out) {
    __shared__ float red[256];
    int t = threadIdx.x;
    const float em = expf(-SHIFT_C);
    float s = 0.0f;
    for (int i = t; i < N_CLS; i += 256)
        s += SHIFT_C + logf(em + sums[i]);
    red[t] = s;
    __syncthreads();
    for (int st = 128; st > 0; st >>= 1) {
        if (t < st) red[t] += red[t + st];
        __syncthreads();
    }
    if (t == 0) out[0] = red[0];
}

extern "C" void kernel_launch(void* const* d_in, const int* in_sizes, int n_in,
                              void* d_out, int out_size, void* d_ws, size_t ws_size,
                              hipStream_t stream) {
    const float* x    = (const float*)d_in[0];
    const int*   aidx = (const int*)d_in[1];
    // d_in[2] (pos_idx) is derivable (1 - anchor_idx); unused.

    float* ap   = (float*)d_ws;          // N_CLS floats
    float* sums = ap + N_CLS;            // N_CLS floats

    prep_kernel<<<N_CLS, 128, 0, stream>>>(x, ap, sums);
    dim3 grid(N_CLS / BN, N_CLS / BM);
    fused_kernel<<<grid, 256, 0, stream>>>(x, aidx, ap, sums);
    finalize_kernel<<<1, 256, 0, stream>>>(sums, (float*)d_out);
}

// Round 3
// 478.560 us; speedup vs baseline: 1.8868x; 1.8868x over previous
//
#include <hip/hip_runtime.h>
#include <hip/hip_bf16.h>
#include <math.h>

#define N_CLS 16384
#define DDIM  128
#define SHIFT_C 50.0f   // fixed LSE shift: max logit ~ +105 << C + 88.7, no overflow

typedef __attribute__((ext_vector_type(8))) short short8;   // 8 bf16 (4 VGPRs)
typedef __attribute__((ext_vector_type(4))) float f32x4;    // MFMA accumulator

#define LDA 136   // 128 + 8 bf16 pad per row -> 272 B stride, breaks bank conflicts

// ---------------------------------------------------------------------------
// prep: ap[i] = dot(x[2i], x[2i+1]) (pair {anchor,pos} = {2i,2i+1}, dot symm);
// gather anchor rows -> Abf (bf16), negative rows -> Bbf (bf16); zero sums.
// ---------------------------------------------------------------------------
__global__ __launch_bounds__(128)
void prep_kernel(const float* __restrict__ x,
                 const int* __restrict__ aidx,
                 float* __restrict__ ap,
                 float* __restrict__ sums,
                 unsigned short* __restrict__ Abf,
                 unsigned short* __restrict__ Bbf) {
    const int i = blockIdx.x;
    const int t = threadIdx.x;  // 0..127
    const float xa = x[(2 * i) * DDIM + t];
    const float xb = x[(2 * i + 1) * DDIM + t];

    const float av = (aidx[i] == 0) ? xa : xb;
    __hip_bfloat16 ah = __float2bfloat16(av);
    __hip_bfloat16 bh = __float2bfloat16(xb);
    Abf[i * DDIM + t] = *(unsigned short*)&ah;
    Bbf[i * DDIM + t] = *(unsigned short*)&bh;

    float prod = xa * xb;
    #pragma unroll
    for (int off = 32; off > 0; off >>= 1)
        prod += __shfl_down(prod, off, 64);
    __shared__ float w[2];
    if ((t & 63) == 0) w[t >> 6] = prod;
    __syncthreads();
    if (t == 0) {
        ap[i] = w[0] + w[1];
        sums[i] = 0.0f;
    }
}

// ---------------------------------------------------------------------------
// fused MFMA: 128x128 S-tile = A-tile @ B-tile^T (K=128, no K-loop);
// e = exp(S - ap[row] - C) diag-masked; rowsum -> atomicAdd(sums[row]).
// 256 threads = 4 waves in 2x2; each wave computes a 64x64 quadrant as
// 4x4 tiles of 16x16 via mfma_f32_16x16x32_bf16 (4 K-chunks -> 64 MFMA/wave).
// ---------------------------------------------------------------------------
__global__ __launch_bounds__(256)
void fused_kernel(const unsigned short* __restrict__ Abf,
                  const unsigned short* __restrict__ Bbf,
                  const float* __restrict__ ap,
                  float* __restrict__ sums) {
    __shared__ unsigned short As[128][LDA];
    __shared__ unsigned short Bs[128][LDA];

    // supertile swizzle: 16x16 tile supertiles bound L2/L3 traffic
    const int bid = blockIdx.x;
    const int st = bid >> 8;
    const int within = bid & 255;
    const int tRow = ((st & 7) << 4) + (within & 15);
    const int tCol = ((st >> 3) << 4) + (within >> 4);
    const int rowBase = tRow * 128;
    const int colBase = tCol * 128;

    const int tid = threadIdx.x;
    const int lane = tid & 63;
    const int quad = lane >> 4;     // 0..3
    const int l15 = lane & 15;      // 0..15
    const int w = tid >> 6;         // wave 0..3
    const int wm = (w >> 1) * 64;   // wave row quadrant
    const int wn = (w & 1) * 64;    // wave col quadrant

    // --- stage A,B tiles: thread t copies 128 B (row t>>1, half t&1) ---
    {
        const int r = tid >> 1;
        const int half = (tid & 1) * 64;  // bf16 element offset
        const uint4* ga = (const uint4*)(Abf + (long)(rowBase + r) * DDIM + half);
        const uint4* gb = (const uint4*)(Bbf + (long)(colBase + r) * DDIM + half);
        uint4* la = (uint4*)&As[r][half];
        uint4* lb = (uint4*)&Bs[r][half];
        #pragma unroll
        for (int j = 0; j < 8; ++j) { la[j] = ga[j]; lb[j] = gb[j]; }
    }
    __syncthreads();

    // --- MFMA: acc[mt][nt] over 4 K-chunks of 32 ---
    f32x4 acc[4][4];
    #pragma unroll
    for (int mt = 0; mt < 4; ++mt)
        #pragma unroll
        for (int nt = 0; nt < 4; ++nt)
            acc[mt][nt] = (f32x4){0.f, 0.f, 0.f, 0.f};

    #pragma unroll
    for (int kc = 0; kc < 4; ++kc) {
        const int ko = kc * 32 + quad * 8;
        short8 af[4], bfr[4];
        #pragma unroll
        for (int mt = 0; mt < 4; ++mt)
            af[mt] = *(const short8*)&As[wm + mt * 16 + l15][ko];
        #pragma unroll
        for (int nt = 0; nt < 4; ++nt)
            bfr[nt] = *(const short8*)&Bs[wn + nt * 16 + l15][ko];
        #pragma unroll
        for (int mt = 0; mt < 4; ++mt)
            #pragma unroll
            for (int nt = 0; nt < 4; ++nt)
                acc[mt][nt] = __builtin_amdgcn_mfma_f32_16x16x32_bf16(
                    af[mt], bfr[nt], acc[mt][nt], 0, 0, 0);
    }

    // --- epilogue: C/D layout col=lane&15, row=quad*4+reg ---
    #pragma unroll
    for (int mt = 0; mt < 4; ++mt) {
        const int rbase = rowBase + wm + mt * 16 + quad * 4;
        #pragma unroll
        for (int reg = 0; reg < 4; ++reg) {
            const int r = rbase + reg;
            const float apr = ap[r] + SHIFT_C;
            float rs = 0.0f;
            #pragma unroll
            for (int nt = 0; nt < 4; ++nt) {
                const int c = colBase + wn + nt * 16 + l15;
                const float e = __expf(acc[mt][nt][reg] - apr);
                rs += (r != c) ? e : 0.0f;
            }
            rs += __shfl_xor(rs, 1, 64);
            rs += __shfl_xor(rs, 2, 64);
            rs += __shfl_xor(rs, 4, 64);
            rs += __shfl_xor(rs, 8, 64);
            if (l15 == 0) atomicAdd(&sums[r], rs);
        }
    }
}

// ---------------------------------------------------------------------------
// finalize: out = sum_i [ C + log(exp(-C) + sums[i]) ]  ( == sum_i log1p(S_i) )
// ---------------------------------------------------------------------------
__global__ __launch_bounds__(256)
void finalize_kernel(const float* __restrict__ sums, float* __restrict__ out) {
    __shared__ float red[256];
    int t = threadIdx.x;
    const float em = expf(-SHIFT_C);
    float s = 0.0f;
    for (int i = t; i < N_CLS; i += 256)
        s += SHIFT_C + logf(em + sums[i]);
    red[t] = s;
    __syncthreads();
    for (int st = 128; st > 0; st >>= 1) {
        if (t < st) red[t] += red[t + st];
        __syncthreads();
    }
    if (t == 0) out[0] = red[0];
}

extern "C" void kernel_launch(void* const* d_in, const int* in_sizes, int n_in,
                              void* d_out, int out_size, void* d_ws, size_t ws_size,
                              hipStream_t stream) {
    const float* x    = (const float*)d_in[0];
    const int*   aidx = (const int*)d_in[1];
    // d_in[2] (pos_idx) derivable; unused.

    float* ap   = (float*)d_ws;                      // 16384 f32
    float* sums = ap + N_CLS;                        // 16384 f32
    unsigned short* Abf = (unsigned short*)(sums + N_CLS);       // 16384x128 bf16 (4 MB)
    unsigned short* Bbf = Abf + (size_t)N_CLS * DDIM;            // 4 MB

    prep_kernel<<<N_CLS, 128, 0, stream>>>(x, aidx, ap, sums, Abf, Bbf);
    fused_kernel<<<(N_CLS / 128) * (N_CLS / 128), 256, 0, stream>>>(Abf, Bbf, ap, sums);
    finalize_kernel<<<1, 256, 0, stream>>>(sums, (float*)d_out);
}

// Round 4
// 384.452 us; speedup vs baseline: 2.3486x; 1.2448x over previous
//
#include <hip/hip_runtime.h>
#include <hip/hip_bf16.h>
#include <math.h>

#define N_CLS 16384
#define DDIM  128
#define SHIFT_C 50.0f   // fixed LSE shift: max logit ~ +105 << C + 88.7, no overflow
#define LDB 136         // bf16 row stride: 272 B -> lanes n,n+8 2-way alias = free

typedef __attribute__((ext_vector_type(8))) short short8;   // 8 bf16 (4 VGPRs)
typedef __attribute__((ext_vector_type(4))) float f32x4;    // MFMA accumulator

__device__ __forceinline__ unsigned short f2bf(float f) {
    __hip_bfloat16 h = __float2bfloat16(f);
    return *(unsigned short*)&h;
}

// ---------------------------------------------------------------------------
// prep: 8 pairs/block, 32 lanes/pair, float4 loads.
//  ap[i] = dot(x[2i], x[2i+1]);  sums[i] = 0
//  Afrag: anchor rows in MFMA A-fragment-major layout:
//    element (row i, k): tile=i>>4, m=i&15, kc=k>>5, q=(k>>3)&3, j=k&7
//    flat = (tile*4+kc)*512 + (q*16+m)*8 + j   -> wave frag = 1024 B contiguous
//  Bbf: negative rows x[2i+1], row-major bf16.
// ---------------------------------------------------------------------------
__global__ __launch_bounds__(256)
void prep_kernel(const float* __restrict__ x,
                 const int* __restrict__ aidx,
                 float* __restrict__ ap,
                 float* __restrict__ sums,
                 unsigned short* __restrict__ Afrag,
                 unsigned short* __restrict__ Bbf) {
    const int t = threadIdx.x;
    const int l = t & 31;                       // lane within pair-group
    const int i = blockIdx.x * 8 + (t >> 5);    // class index
    const float4 xa = *(const float4*)(x + (2L * i) * DDIM + l * 4);
    const float4 xb = *(const float4*)(x + (2L * i + 1) * DDIM + l * 4);
    const float4 av = (aidx[i] == 0) ? xa : xb;

    // A fragment-major write (8 B per thread)
    const int kc = l >> 3, q = (l >> 1) & 3, j0 = (l & 1) * 4;
    unsigned short* adst = Afrag + ((long)((i >> 4) * 4 + kc)) * 512
                                 + (q * 16 + (i & 15)) * 8 + j0;
    ushort4 a4; a4.x = f2bf(av.x); a4.y = f2bf(av.y); a4.z = f2bf(av.z); a4.w = f2bf(av.w);
    *(ushort4*)adst = a4;

    // B row-major write (8 B per thread, coalesced)
    ushort4 b4; b4.x = f2bf(xb.x); b4.y = f2bf(xb.y); b4.z = f2bf(xb.z); b4.w = f2bf(xb.w);
    *(ushort4*)(Bbf + (long)i * DDIM + l * 4) = b4;

    // ap = dot(x[2i], x[2i+1]) in fp32
    float d = xa.x * xb.x + xa.y * xb.y + xa.z * xb.z + xa.w * xb.w;
    d += __shfl_xor(d, 1, 64);
    d += __shfl_xor(d, 2, 64);
    d += __shfl_xor(d, 4, 64);
    d += __shfl_xor(d, 8, 64);
    d += __shfl_xor(d, 16, 64);
    if (l == 0) { ap[i] = d; sums[i] = 0.0f; }
}

// ---------------------------------------------------------------------------
// fused: block = (col-tile c of 128, row-group g of 2048). B tile staged to
// LDS ONCE; loop over 8 slabs of 256 rows (wave w -> 64 rows = 4 M-tiles).
// Per wave-iter: 128 x mfma_f32_16x16x32_bf16, A frags streamed from global
// (fragment-major, coalesced), exp epilogue, 4-step shuffle rowsum, atomicAdd.
// No __syncthreads inside the loop.
// ---------------------------------------------------------------------------
__global__ __launch_bounds__(256, 2)
void fused_kernel(const unsigned short* __restrict__ Afrag,
                  const unsigned short* __restrict__ Bbf,
                  const float* __restrict__ ap,
                  float* __restrict__ sums) {
    __shared__ unsigned short Bs[128][LDB];

    const int tid = threadIdx.x;
    const int lane = tid & 63;
    const int w = tid >> 6;                 // wave 0..3
    const int quad = lane >> 4;             // 0..3
    const int l15 = lane & 15;              // 0..15
    const int c = blockIdx.x & 127;
    const int g = blockIdx.x >> 7;
    const int colBase = c * 128;

    // --- stage B tile once: thread -> row tid>>1, 64-elem half tid&1 ---
    {
        const int r = tid >> 1;
        const int half = (tid & 1) * 64;
        const uint4* gb = (const uint4*)(Bbf + (long)(colBase + r) * DDIM + half);
        uint4* lb = (uint4*)&Bs[r][half];
        #pragma unroll
        for (int j = 0; j < 8; ++j) lb[j] = gb[j];
    }
    __syncthreads();

    for (int it = 0; it < 8; ++it) {
        const int rowBase = g * 2048 + it * 256 + w * 64;   // 4 M-tiles of 16

        f32x4 acc[4][8];
        #pragma unroll
        for (int mt = 0; mt < 4; ++mt)
            #pragma unroll
            for (int nt = 0; nt < 8; ++nt)
                acc[mt][nt] = (f32x4){0.f, 0.f, 0.f, 0.f};

        const unsigned short* abase = Afrag + ((long)(rowBase >> 4)) * 2048 + lane * 8;

        #pragma unroll
        for (int kc = 0; kc < 4; ++kc) {
            short8 bfr[8];
            #pragma unroll
            for (int nt = 0; nt < 8; ++nt)
                bfr[nt] = *(const short8*)&Bs[nt * 16 + l15][kc * 32 + quad * 8];
            short8 af[4];
            #pragma unroll
            for (int mt = 0; mt < 4; ++mt)
                af[mt] = *(const short8*)(abase + (mt * 4 + kc) * 512);
            #pragma unroll
            for (int mt = 0; mt < 4; ++mt)
                #pragma unroll
                for (int nt = 0; nt < 8; ++nt)
                    acc[mt][nt] = __builtin_amdgcn_mfma_f32_16x16x32_bf16(
                        af[mt], bfr[nt], acc[mt][nt], 0, 0, 0);
        }

        // --- epilogue: C/D layout col=lane&15, row=quad*4+reg ---
        #pragma unroll
        for (int mt = 0; mt < 4; ++mt) {
            #pragma unroll
            for (int reg = 0; reg < 4; ++reg) {
                const int r = rowBase + mt * 16 + quad * 4 + reg;
                const float apr = ap[r] + SHIFT_C;
                float rs = 0.0f;
                #pragma unroll
                for (int nt = 0; nt < 8; ++nt) {
                    const int cc = colBase + nt * 16 + l15;
                    const float e = __expf(acc[mt][nt][reg] - apr);
                    rs += (r != cc) ? e : 0.0f;
                }
                rs += __shfl_xor(rs, 1, 64);
                rs += __shfl_xor(rs, 2, 64);
                rs += __shfl_xor(rs, 4, 64);
                rs += __shfl_xor(rs, 8, 64);
                if (l15 == 0) atomicAdd(&sums[r], rs);
            }
        }
    }
}

// ---------------------------------------------------------------------------
// finalize: out = sum_i [ C + log(exp(-C) + sums[i]) ]  ( == sum_i log1p(S_i) )
// ---------------------------------------------------------------------------
__global__ __launch_bounds__(256)
void finalize_kernel(const float* __restrict__ sums, float* __restrict__ out) {
    __shared__ float red[256];
    int t = threadIdx.x;
    const float em = expf(-SHIFT_C);
    float s = 0.0f;
    for (int i = t; i < N_CLS; i += 256)
        s += SHIFT_C + logf(em + sums[i]);
    red[t] = s;
    __syncthreads();
    for (int st = 128; st > 0; st >>= 1) {
        if (t < st) red[t] += red[t + st];
        __syncthreads();
    }
    if (t == 0) out[0] = red[0];
}

extern "C" void kernel_launch(void* const* d_in, const int* in_sizes, int n_in,
                              void* d_out, int out_size, void* d_ws, size_t ws_size,
                              hipStream_t stream) {
    const float* x    = (const float*)d_in[0];
    const int*   aidx = (const int*)d_in[1];
    // d_in[2] (pos_idx) derivable; unused.

    float* ap   = (float*)d_ws;                            // 16384 f32
    float* sums = ap + N_CLS;                              // 16384 f32
    unsigned short* Afrag = (unsigned short*)(sums + N_CLS);   // 4 MB, fragment-major
    unsigned short* Bbf   = Afrag + (size_t)N_CLS * DDIM;      // 4 MB, row-major

    prep_kernel<<<N_CLS / 8, 256, 0, stream>>>(x, aidx, ap, sums, Afrag, Bbf);
    fused_kernel<<<128 * 8, 256, 0, stream>>>(Afrag, Bbf, ap, sums);
    finalize_kernel<<<1, 256, 0, stream>>>(sums, (float*)d_out);
}

// Round 5
// 156.106 us; speedup vs baseline: 5.7842x; 2.4628x over previous
//
#include <hip/hip_runtime.h>
#include <hip/hip_bf16.h>
#include <math.h>

#define N_CLS 16384
#define DDIM  128
#define CSHIFT 50.0f    // fixed shift: S = a.n has |S| <~ 70; exp(S-50) never overflows,
                        // and exp(-ap) is folded back in log-domain at finalize.
#define LDA 136         // bf16 row stride pad (272 B) — conflict-free per round-4 counter

typedef __attribute__((ext_vector_type(8))) short short8;   // 8 bf16 (4 VGPRs)
typedef __attribute__((ext_vector_type(4))) float f32x4;    // MFMA accumulator

__device__ __forceinline__ unsigned short f2bf(float f) {
    __hip_bfloat16 h = __float2bfloat16(f);
    return *(unsigned short*)&h;
}

// ---------------------------------------------------------------------------
// prep: 8 pairs/block, 32 lanes/pair.
//   ap[i]   = dot(x[2i], x[2i+1])            (fp32)
//   Abf     = anchor rows, row-major bf16    (staged to LDS by fused)
//   Bfrag   = negative rows, MFMA-B-fragment-major bf16:
//     value B[col=c][k] at ((c>>4)*4 + (k>>5))*512 + (((k>>3)&3)*16 + (c&15))*8 + (k&7)
// ---------------------------------------------------------------------------
__global__ __launch_bounds__(256)
void prep_kernel(const float* __restrict__ x,
                 const int* __restrict__ aidx,
                 float* __restrict__ ap,
                 unsigned short* __restrict__ Abf,
                 unsigned short* __restrict__ Bfrag) {
    const int t = threadIdx.x;
    const int l = t & 31;                       // lane within pair-group
    const int i = blockIdx.x * 8 + (t >> 5);    // class index
    const float4 xa = *(const float4*)(x + (2L * i) * DDIM + l * 4);
    const float4 xb = *(const float4*)(x + (2L * i + 1) * DDIM + l * 4);
    const float4 av = (aidx[i] == 0) ? xa : xb;

    // A row-major (coalesced)
    ushort4 a4; a4.x = f2bf(av.x); a4.y = f2bf(av.y); a4.z = f2bf(av.z); a4.w = f2bf(av.w);
    *(ushort4*)(Abf + (long)i * DDIM + l * 4) = a4;

    // B fragment-major: this thread owns k = l*4..l*4+3
    const int kc = l >> 3, q = (l >> 1) & 3, j0 = (l & 1) * 4;
    ushort4 b4; b4.x = f2bf(xb.x); b4.y = f2bf(xb.y); b4.z = f2bf(xb.z); b4.w = f2bf(xb.w);
    *(ushort4*)(Bfrag + ((long)((i >> 4) * 4 + kc)) * 512 + (q * 16 + (i & 15)) * 8 + j0) = b4;

    // ap
    float d = xa.x * xb.x + xa.y * xb.y + xa.z * xb.z + xa.w * xb.w;
    d += __shfl_xor(d, 1, 64);
    d += __shfl_xor(d, 2, 64);
    d += __shfl_xor(d, 4, 64);
    d += __shfl_xor(d, 8, 64);
    d += __shfl_xor(d, 16, 64);
    if (l == 0) ap[i] = d;
}

// ---------------------------------------------------------------------------
// fused: block = (row-tile rt: 128 rows, col-octant oct = bid&7 -> XCD-aligned).
// A-tile in LDS once (no barrier in loop). Sweep 16 col-tiles of 128; waves 2x2
// over 64x64 subtiles; B frags streamed from L2-resident fragment-major octant.
// rowsum accumulates in REGISTERS (shift C); one plain store per (row, slot).
// ---------------------------------------------------------------------------
__global__ __launch_bounds__(256)
void fused_kernel(const unsigned short* __restrict__ Abf,
                  const unsigned short* __restrict__ Bfrag,
                  float* __restrict__ partial) {
    __shared__ unsigned short As[128][LDA];

    const int tid = threadIdx.x;
    const int lane = tid & 63;
    const int w = tid >> 6;                 // wave 0..3
    const int quad = lane >> 4;             // 0..3
    const int l15 = lane & 15;              // 0..15
    const int oct = blockIdx.x & 7;         // XCD-aligned column octant
    const int rt = blockIdx.x >> 3;         // row tile 0..127
    const int rowBase = rt * 128;
    const int wm = (w >> 1) * 64;           // wave row offset
    const int wh = w & 1;                   // wave col half
    const int wn = wh * 64;

    // stage A tile (32 KB), coalesced 128 B/thread
    {
        const int r = tid >> 1;
        const int half = (tid & 1) * 64;
        const uint4* ga = (const uint4*)(Abf + (long)(rowBase + r) * DDIM + half);
        uint4* la = (uint4*)&As[r][half];
        #pragma unroll
        for (int j = 0; j < 8; ++j) la[j] = ga[j];
    }
    __syncthreads();

    float rs[4][4];
    #pragma unroll
    for (int mt = 0; mt < 4; ++mt)
        #pragma unroll
        for (int reg = 0; reg < 4; ++reg) rs[mt][reg] = 0.0f;

    // B fragment base for this wave's column half
    const unsigned short* bbase = Bfrag + ((long)(oct * 128 + wh * 4) * 4) * 512 + lane * 8;

    for (int it = 0; it < 16; ++it) {
        const int ct = oct * 16 + it;

        f32x4 acc[4][4];
        #pragma unroll
        for (int mt = 0; mt < 4; ++mt)
            #pragma unroll
            for (int nt = 0; nt < 4; ++nt) acc[mt][nt] = (f32x4){0.f, 0.f, 0.f, 0.f};

        #pragma unroll
        for (int kc = 0; kc < 4; ++kc) {
            short8 af[4], bfr[4];
            #pragma unroll
            for (int mt = 0; mt < 4; ++mt)
                af[mt] = *(const short8*)&As[wm + mt * 16 + l15][kc * 32 + quad * 8];
            #pragma unroll
            for (int nt = 0; nt < 4; ++nt)
                bfr[nt] = *(const short8*)(bbase + (long)it * 16384 + (nt * 4 + kc) * 512);
            #pragma unroll
            for (int mt = 0; mt < 4; ++mt)
                #pragma unroll
                for (int nt = 0; nt < 4; ++nt)
                    acc[mt][nt] = __builtin_amdgcn_mfma_f32_16x16x32_bf16(
                        af[mt], bfr[nt], acc[mt][nt], 0, 0, 0);
        }

        // epilogue: e = exp(S - C); diagonal only possible when ct == rt
        const int colBase = ct * 128 + wn;
        if (ct == rt) {
            #pragma unroll
            for (int mt = 0; mt < 4; ++mt)
                #pragma unroll
                for (int nt = 0; nt < 4; ++nt)
                    #pragma unroll
                    for (int reg = 0; reg < 4; ++reg) {
                        const int r = rowBase + wm + mt * 16 + quad * 4 + reg;
                        const int c = colBase + nt * 16 + l15;
                        const float e = __expf(acc[mt][nt][reg] - CSHIFT);
                        rs[mt][reg] += (r != c) ? e : 0.0f;
                    }
        } else {
            #pragma unroll
            for (int mt = 0; mt < 4; ++mt)
                #pragma unroll
                for (int nt = 0; nt < 4; ++nt)
                    #pragma unroll
                    for (int reg = 0; reg < 4; ++reg)
                        rs[mt][reg] += __expf(acc[mt][nt][reg] - CSHIFT);
        }
    }

    // cross-l15 reduce, one plain store per row into slot (oct, col-half)
    const int slot = oct * 2 + wh;          // 16 slots
    #pragma unroll
    for (int mt = 0; mt < 4; ++mt)
        #pragma unroll
        for (int reg = 0; reg < 4; ++reg) {
            float v = rs[mt][reg];
            v += __shfl_xor(v, 1, 64);
            v += __shfl_xor(v, 2, 64);
            v += __shfl_xor(v, 4, 64);
            v += __shfl_xor(v, 8, 64);
            if (l15 == 0)
                partial[(long)slot * N_CLS + rowBase + wm + mt * 16 + quad * 4 + reg] = v;
        }
}

// ---------------------------------------------------------------------------
// finalize1: per row, s = sum of 16 slot partials; row loss =
//   log1p(s * exp(C - ap)) computed stably as u = log(s) + C - ap.
// Block-sum -> bsum[bid].
// ---------------------------------------------------------------------------
__global__ __launch_bounds__(256)
void finalize1_kernel(const float* __restrict__ partial,
                      const float* __restrict__ ap,
                      float* __restrict__ bsum) {
    __shared__ float red[256];
    const int t = threadIdx.x;
    const int row = blockIdx.x * 256 + t;
    float s = 0.0f;
    #pragma unroll
    for (int p = 0; p < 16; ++p) s += partial[(long)p * N_CLS + row];
    const float u = logf(s) + (CSHIFT - ap[row]);   // s==0 -> -inf -> loss 0
    const float loss = (u > 25.0f) ? u : log1pf(__expf(u));
    red[t] = loss;
    __syncthreads();
    for (int st = 128; st > 0; st >>= 1) {
        if (t < st) red[t] += red[t + st];
        __syncthreads();
    }
    if (t == 0) bsum[blockIdx.x] = red[0];
}

__global__ __launch_bounds__(64)
void finalize2_kernel(const float* __restrict__ bsum, float* __restrict__ out) {
    float v = bsum[threadIdx.x];
    #pragma unroll
    for (int off = 32; off > 0; off >>= 1) v += __shfl_down(v, off, 64);
    if (threadIdx.x == 0) out[0] = v;
}

extern "C" void kernel_launch(void* const* d_in, const int* in_sizes, int n_in,
                              void* d_out, int out_size, void* d_ws, size_t ws_size,
                              hipStream_t stream) {
    const float* x    = (const float*)d_in[0];
    const int*   aidx = (const int*)d_in[1];
    // d_in[2] (pos_idx) derivable; unused.

    char* ws = (char*)d_ws;
    float* ap            = (float*)(ws);                    // 64 KB
    float* bsum          = (float*)(ws + 65536);            // 256 B
    float* partial       = (float*)(ws + 131072);           // 16*16384*4 = 1 MB
    unsigned short* Abf  = (unsigned short*)(ws + 131072 + 1048576);          // 4 MB
    unsigned short* Bfrag= (unsigned short*)(ws + 131072 + 1048576 + 4194304);// 4 MB

    prep_kernel<<<N_CLS / 8, 256, 0, stream>>>(x, aidx, ap, Abf, Bfrag);
    fused_kernel<<<1024, 256, 0, stream>>>(Abf, Bfrag, partial);
    finalize1_kernel<<<64, 256, 0, stream>>>(partial, ap, bsum);
    finalize2_kernel<<<1, 64, 0, stream>>>(bsum, (float*)d_out);
}

// Round 6
// 142.714 us; speedup vs baseline: 6.3269x; 1.0938x over previous
//
#include <hip/hip_runtime.h>
#include <hip/hip_bf16.h>
#include <math.h>

#define N_CLS 16384
#define DDIM  128
#define CSHIFT 50.0f    // fixed shift; exp(-ap) folded back in log domain at finalize
#define LOG2E 1.4426950408889634f
#define NEGC2 (-72.13475204444817f)   // -CSHIFT*LOG2E — acc init, so acc = S*log2e - C*log2e

#if __has_builtin(__builtin_amdgcn_exp2f)
#define EXP2(x) __builtin_amdgcn_exp2f(x)
#else
#define EXP2(x) exp2f(x)
#endif

typedef __attribute__((ext_vector_type(8))) short short8;   // 8 bf16 (4 VGPRs)
typedef __attribute__((ext_vector_type(4))) float f32x4;    // MFMA accumulator

__device__ __forceinline__ unsigned short f2bf(float f) {
    __hip_bfloat16 h = __float2bfloat16(f);
    return *(unsigned short*)&h;
}

// ---------------------------------------------------------------------------
// Fragment-major layout for mfma_f32_16x16x32_bf16 operands:
//   X[row r][k] -> ((r>>4)*4 + (k>>5))*512 + (((k>>3)&3)*16 + (r&15))*8 + (k&7)
// so one 16x16x32 fragment = 1024 contiguous bytes, lane-ordered (16 B/lane).
//
// prep: 8 pairs/block, 32 lanes/pair.
//   ap[i] = dot(x[2i], x[2i+1]) fp32 (pair {anchor,pos}={2i,2i+1}, dot symm)
//   Afrag = anchor rows * LOG2E  (bf16, fragment-major)
//   Bfrag = negative rows        (bf16, fragment-major)
//   also zeroes out[0] (finalize atomicAdds into it; stream-ordered).
// ---------------------------------------------------------------------------
__global__ __launch_bounds__(256)
void prep_kernel(const float* __restrict__ x,
                 const int* __restrict__ aidx,
                 float* __restrict__ ap,
                 unsigned short* __restrict__ Afrag,
                 unsigned short* __restrict__ Bfrag,
                 float* __restrict__ out) {
    const int t = threadIdx.x;
    const int l = t & 31;                       // lane within pair-group: k = l*4..l*4+3
    const int i = blockIdx.x * 8 + (t >> 5);    // class index
    const float4 xa = *(const float4*)(x + (2L * i) * DDIM + l * 4);
    const float4 xb = *(const float4*)(x + (2L * i + 1) * DDIM + l * 4);
    const float4 av = (aidx[i] == 0) ? xa : xb;

    const int kc = l >> 3, q = (l >> 1) & 3, j0 = (l & 1) * 4;
    const long base = ((long)((i >> 4) * 4 + kc)) * 512 + (q * 16 + (i & 15)) * 8 + j0;

    ushort4 a4;
    a4.x = f2bf(av.x * LOG2E); a4.y = f2bf(av.y * LOG2E);
    a4.z = f2bf(av.z * LOG2E); a4.w = f2bf(av.w * LOG2E);
    *(ushort4*)(Afrag + base) = a4;

    ushort4 b4;
    b4.x = f2bf(xb.x); b4.y = f2bf(xb.y); b4.z = f2bf(xb.z); b4.w = f2bf(xb.w);
    *(ushort4*)(Bfrag + base) = b4;

    float d = xa.x * xb.x + xa.y * xb.y + xa.z * xb.z + xa.w * xb.w;
    d += __shfl_xor(d, 1, 64);
    d += __shfl_xor(d, 2, 64);
    d += __shfl_xor(d, 4, 64);
    d += __shfl_xor(d, 8, 64);
    d += __shfl_xor(d, 16, 64);
    if (l == 0) ap[i] = d;
    if (blockIdx.x == 0 && t == 0) out[0] = 0.0f;
}

// ---------------------------------------------------------------------------
// fused: block = (row-tile rt = bid>>3, col-octant oct = bid&7, XCD-aligned).
// NO LDS, NO barriers. A frags (16 x short8 = 64 VGPRs) hoisted to registers
// for the whole 16-col-tile sweep; B frags stream from the L2-resident
// fragment-major octant with kc-level ping-pong prefetch. acc initialized to
// -C*log2e so the epilogue is exp2 + add only. Row-sums live in registers;
// one plain store per (row, slot) at the end.
// ---------------------------------------------------------------------------
__global__ __launch_bounds__(256, 2)
void fused_kernel(const unsigned short* __restrict__ Afrag,
                  const unsigned short* __restrict__ Bfrag,
                  float* __restrict__ partial) {
    const int tid = threadIdx.x;
    const int lane = tid & 63;
    const int w = tid >> 6;                 // wave 0..3
    const int quad = lane >> 4;             // 0..3
    const int l15 = lane & 15;              // 0..15
    const int oct = blockIdx.x & 7;         // XCD-aligned column octant
    const int rt = blockIdx.x >> 3;         // row tile 0..127
    const int wm2 = w >> 1;                 // wave row half
    const int wh = w & 1;                   // wave col half

    // hoist A fragments (rows rt*128 + wm2*64 + mt*16, all 4 kc)
    short8 af[4][4];
    {
        const unsigned short* abase =
            Afrag + ((long)(rt * 8 + wm2 * 4) * 4) * 512 + lane * 8;
        #pragma unroll
        for (int mt = 0; mt < 4; ++mt)
            #pragma unroll
            for (int kc = 0; kc < 4; ++kc)
                af[mt][kc] = *(const short8*)(abase + (mt * 4 + kc) * 512);
    }

    // B base for this wave's column half; tile (it,nt,kc) at
    // itoff = it*16384 (+ (nt*4+kc)*512) relative to bbase (units: ushort)
    const unsigned short* bbase =
        Bfrag + ((long)(oct * 128 + wh * 4) * 4) * 512 + lane * 8;

    float rs[4][4] = {};
    short8 bA[4], bB[4];
    #pragma unroll
    for (int nt = 0; nt < 4; ++nt)
        bA[nt] = *(const short8*)(bbase + nt * 4 * 512);

    for (int it = 0; it < 16; ++it) {
        const long itoff = (long)it * 16384;
        const long nxoff = (it < 15) ? itoff + 16384 : itoff;  // clamp last prefetch

        f32x4 acc[4][4];
        #pragma unroll
        for (int mt = 0; mt < 4; ++mt)
            #pragma unroll
            for (int nt = 0; nt < 4; ++nt)
                acc[mt][nt] = (f32x4){NEGC2, NEGC2, NEGC2, NEGC2};

        // kc=0: consume bA, prefetch kc=1 -> bB
        #pragma unroll
        for (int nt = 0; nt < 4; ++nt)
            bB[nt] = *(const short8*)(bbase + itoff + (nt * 4 + 1) * 512);
        #pragma unroll
        for (int mt = 0; mt < 4; ++mt)
            #pragma unroll
            for (int nt = 0; nt < 4; ++nt)
                acc[mt][nt] = __builtin_amdgcn_mfma_f32_16x16x32_bf16(
                    af[mt][0], bA[nt], acc[mt][nt], 0, 0, 0);

        // kc=1: consume bB, prefetch kc=2 -> bA
        #pragma unroll
        for (int nt = 0; nt < 4; ++nt)
            bA[nt] = *(const short8*)(bbase + itoff + (nt * 4 + 2) * 512);
        #pragma unroll
        for (int mt = 0; mt < 4; ++mt)
            #pragma unroll
            for (int nt = 0; nt < 4; ++nt)
                acc[mt][nt] = __builtin_amdgcn_mfma_f32_16x16x32_bf16(
                    af[mt][1], bB[nt], acc[mt][nt], 0, 0, 0);

        // kc=2: consume bA, prefetch kc=3 -> bB
        #pragma unroll
        for (int nt = 0; nt < 4; ++nt)
            bB[nt] = *(const short8*)(bbase + itoff + (nt * 4 + 3) * 512);
        #pragma unroll
        for (int mt = 0; mt < 4; ++mt)
            #pragma unroll
            for (int nt = 0; nt < 4; ++nt)
                acc[mt][nt] = __builtin_amdgcn_mfma_f32_16x16x32_bf16(
                    af[mt][2], bA[nt], acc[mt][nt], 0, 0, 0);

        // kc=3: consume bB, prefetch next iter kc=0 -> bA
        #pragma unroll
        for (int nt = 0; nt < 4; ++nt)
            bA[nt] = *(const short8*)(bbase + nxoff + nt * 4 * 512);
        #pragma unroll
        for (int mt = 0; mt < 4; ++mt)
            #pragma unroll
            for (int nt = 0; nt < 4; ++nt)
                acc[mt][nt] = __builtin_amdgcn_mfma_f32_16x16x32_bf16(
                    af[mt][3], bB[nt], acc[mt][nt], 0, 0, 0);

        // epilogue: acc = S*log2e - C*log2e -> e = 2^acc = exp(S - C)
        const int ct = oct * 16 + it;
        if (ct == rt) {
            #pragma unroll
            for (int mt = 0; mt < 4; ++mt)
                #pragma unroll
                for (int nt = 0; nt < 4; ++nt)
                    #pragma unroll
                    for (int reg = 0; reg < 4; ++reg) {
                        const bool diag = (wm2 == wh) && (mt == nt) &&
                                          (quad * 4 + reg == l15);
                        const float e = EXP2(acc[mt][nt][reg]);
                        rs[mt][reg] += diag ? 0.0f : e;
                    }
        } else {
            #pragma unroll
            for (int mt = 0; mt < 4; ++mt)
                #pragma unroll
                for (int nt = 0; nt < 4; ++nt)
                    #pragma unroll
                    for (int reg = 0; reg < 4; ++reg)
                        rs[mt][reg] += EXP2(acc[mt][nt][reg]);
        }
    }

    // cross-l15 reduce, plain store into slot (oct, col-half)
    const int slot = oct * 2 + wh;          // 16 slots
    const int rowBase = rt * 128 + wm2 * 64;
    #pragma unroll
    for (int mt = 0; mt < 4; ++mt)
        #pragma unroll
        for (int reg = 0; reg < 4; ++reg) {
            float v = rs[mt][reg];
            v += __shfl_xor(v, 1, 64);
            v += __shfl_xor(v, 2, 64);
            v += __shfl_xor(v, 4, 64);
            v += __shfl_xor(v, 8, 64);
            if (l15 == 0)
                partial[(long)slot * N_CLS + rowBase + mt * 16 + quad * 4 + reg] = v;
        }
}

// ---------------------------------------------------------------------------
// finalize: per row s = sum of 16 slot partials (= sum_j exp(S_ij - C), j!=i);
// loss = log1p(s * exp(C - ap)) via u = log(s) + C - ap; block-sum; atomicAdd.
// ---------------------------------------------------------------------------
__global__ __launch_bounds__(256)
void finalize_kernel(const float* __restrict__ partial,
                     const float* __restrict__ ap,
                     float* __restrict__ out) {
    __shared__ float red[256];
    const int t = threadIdx.x;
    const int row = blockIdx.x * 256 + t;
    float s = 0.0f;
    #pragma unroll
    for (int p = 0; p < 16; ++p) s += partial[(long)p * N_CLS + row];
    const float u = logf(s) + (CSHIFT - ap[row]);
    const float loss = (u > 25.0f) ? u : log1pf(__expf(u));
    red[t] = loss;
    __syncthreads();
    for (int st = 128; st > 0; st >>= 1) {
        if (t < st) red[t] += red[t + st];
        __syncthreads();
    }
    if (t == 0) atomicAdd(out, red[0]);
}

extern "C" void kernel_launch(void* const* d_in, const int* in_sizes, int n_in,
                              void* d_out, int out_size, void* d_ws, size_t ws_size,
                              hipStream_t stream) {
    const float* x    = (const float*)d_in[0];
    const int*   aidx = (const int*)d_in[1];
    // d_in[2] (pos_idx) derivable; unused.

    char* ws = (char*)d_ws;
    float* ap             = (float*)(ws);                                   // 64 KB
    float* partial        = (float*)(ws + 131072);                          // 1 MB
    unsigned short* Afrag = (unsigned short*)(ws + 131072 + 1048576);       // 4 MB
    unsigned short* Bfrag = (unsigned short*)(ws + 131072 + 1048576 + 4194304); // 4 MB

    prep_kernel<<<N_CLS / 8, 256, 0, stream>>>(x, aidx, ap, Afrag, Bfrag, (float*)d_out);
    fused_kernel<<<1024, 256, 0, stream>>>(Afrag, Bfrag, partial);
    finalize_kernel<<<64, 256, 0, stream>>>(partial, ap, (float*)d_out);
}